// Round 1
// baseline (215.443 us; speedup 1.0000x reference)
//
#include <hip/hip_runtime.h>
#include <hip/hip_bf16.h>

// ---------------------------------------------------------------------------
// LogicLayer fused implementation (MI355X / gfx950)
// Shapes: B=4, N=48, C=16, H=64; CIN = {48,64,128,192}, COUT=16
// y3 (B*N^3 rows, MLP 192->64->16) dominates: done with bf16 MFMA 16x16x32.
// ---------------------------------------------------------------------------

typedef __bf16 bf16x8 __attribute__((ext_vector_type(8)));
typedef unsigned short us8 __attribute__((ext_vector_type(8)));
typedef float f32x4 __attribute__((ext_vector_type(4)));

__device__ __forceinline__ unsigned short f2bf(float f) {
    __hip_bfloat16 h = __float2bfloat16(f);   // RNE
    return __builtin_bit_cast(unsigned short, h);
}
__device__ __forceinline__ unsigned int pk2(float a, float b) {
    return (unsigned int)f2bf(a) | ((unsigned int)f2bf(b) << 16);
}
__device__ __forceinline__ float sigmoidf_(float z) {
    return 1.0f / (1.0f + __expf(-z));
}
__device__ __forceinline__ bf16x8 ld_bf8(const unsigned short* p) {
    return __builtin_bit_cast(bf16x8, *(const us8*)p);
}

// ---------------------------------------------------------------------------
// Shared MLP head: GEMM1 [48 x (NK*32)] @ W1 -> relu -> GEMM2 [48x64] @ W2
// -> sigmoid -> out rows [48][16].  192 threads = 3 waves; wave w owns rows
// 16w..16w+15.  MFMA 16x16x32 bf16 layouts (m89/m91/m92-verified):
//   A: row = lane&15, k = (lane>>4)*8 + e   (8 consecutive k -> ds_read_b128)
//   B: col = lane&15, k = (lane>>4)*8 + e   (W1 stored transposed [h][k])
//   D: col = lane&15, row = (lane>>4)*4 + reg
// ---------------------------------------------------------------------------
template <int NK>
__device__ __forceinline__ void mlp_head(
    const unsigned short* lds_in,   // [48][NK*32+8]
    const unsigned short* lds_w1t,  // [64][NK*32+8]  (W1 transposed)
    const unsigned short* lds_w2t,  // [16][72]       (W2 transposed)
    const float* lds_b1, const float* lds_b2,
    unsigned short* lds_h,          // [48][72]
    float* outp)                    // row-major [48][16]
{
    constexpr int S = NK * 32 + 8;
    const int t = threadIdx.x;
    const int w = t >> 6, lr = t & 15, lg = (t >> 4) & 3;

    f32x4 acc0 = {0.f, 0.f, 0.f, 0.f};
    f32x4 acc1 = acc0, acc2 = acc0, acc3 = acc0;
    const unsigned short* pa = lds_in + (16 * w + lr) * S + lg * 8;
    const unsigned short* pb = lds_w1t + lr * S + lg * 8;
#pragma unroll
    for (int ks = 0; ks < NK; ++ks) {
        bf16x8 a = ld_bf8(pa + ks * 32);
        acc0 = __builtin_amdgcn_mfma_f32_16x16x32_bf16(a, ld_bf8(pb + 0 * 16 * S + ks * 32), acc0, 0, 0, 0);
        acc1 = __builtin_amdgcn_mfma_f32_16x16x32_bf16(a, ld_bf8(pb + 1 * 16 * S + ks * 32), acc1, 0, 0, 0);
        acc2 = __builtin_amdgcn_mfma_f32_16x16x32_bf16(a, ld_bf8(pb + 2 * 16 * S + ks * 32), acc2, 0, 0, 0);
        acc3 = __builtin_amdgcn_mfma_f32_16x16x32_bf16(a, ld_bf8(pb + 3 * 16 * S + ks * 32), acc3, 0, 0, 0);
    }
    const int hrow = 16 * w + lg * 4;
#pragma unroll
    for (int r = 0; r < 4; ++r) {
        lds_h[(hrow + r) * 72 +  0 + lr] = f2bf(fmaxf(acc0[r] + lds_b1[ 0 + lr], 0.f));
        lds_h[(hrow + r) * 72 + 16 + lr] = f2bf(fmaxf(acc1[r] + lds_b1[16 + lr], 0.f));
        lds_h[(hrow + r) * 72 + 32 + lr] = f2bf(fmaxf(acc2[r] + lds_b1[32 + lr], 0.f));
        lds_h[(hrow + r) * 72 + 48 + lr] = f2bf(fmaxf(acc3[r] + lds_b1[48 + lr], 0.f));
    }
    __syncthreads();
    f32x4 o = {0.f, 0.f, 0.f, 0.f};
#pragma unroll
    for (int ks = 0; ks < 2; ++ks) {
        bf16x8 a = ld_bf8(lds_h + (16 * w + lr) * 72 + ks * 32 + lg * 8);
        bf16x8 b = ld_bf8(lds_w2t + lr * 72 + ks * 32 + lg * 8);
        o = __builtin_amdgcn_mfma_f32_16x16x32_bf16(a, b, o, 0, 0, 0);
    }
    const float b2v = lds_b2[lr];
#pragma unroll
    for (int r = 0; r < 4; ++r)
        outp[(hrow + r) * 16 + lr] = sigmoidf_(o[r] + b2v);
}

// ---------------------------------------------------------------------------
// y3: rows (b,i,j,k).  in192 channels per perm q (itertools order):
//  q0 (i,j,k)  q1 (i,k,j)  q2 (j,i,k)  q3 (k,i,j)  q4 (j,k,i)  q5 (k,j,i)
//  ch[32q..32q+15] = x2[b,m1,m2,:],  ch[32q+16..32q+31] = x3[b,m1,m2,m3,:]
// One wg per (b,i,j); 9 tiles per block to amortize weight staging.
// ---------------------------------------------------------------------------
__global__ __launch_bounds__(192) void y3_kernel(
    const float* __restrict__ x2, const float* __restrict__ x3,
    const float* __restrict__ W1, const float* __restrict__ b1,
    const float* __restrict__ W2, const float* __restrict__ b2,
    float* __restrict__ out)
{
    __shared__ __align__(16) unsigned short lds_in[48 * 200];
    __shared__ __align__(16) unsigned short lds_w1t[64 * 200];
    __shared__ __align__(16) unsigned short lds_w2t[16 * 72];
    __shared__ __align__(16) unsigned short lds_h[48 * 72];
    __shared__ float lds_b1[64];
    __shared__ float lds_b2[16];
    const int t = threadIdx.x;

    // Stage weights once per block.  W1: [192][64] -> W1T bf16 [64][200]
#pragma unroll 4
    for (int p = 0; p < 32; ++p) {
        int e = p * 192 + t;
        int h = e & 63, c2 = e >> 6;  // c2 in [0,96)
        *(unsigned int*)(lds_w1t + h * 200 + 2 * c2) =
            pk2(W1[(2 * c2) * 64 + h], W1[(2 * c2 + 1) * 64 + h]);
    }
    for (int p = 0; p < 3; ++p) {
        int e = p * 192 + t;
        if (e < 512) {
            int n = e & 15, k2 = e >> 4;  // k2 in [0,32)
            *(unsigned int*)(lds_w2t + n * 72 + 2 * k2) =
                pk2(W2[(2 * k2) * 16 + n], W2[(2 * k2 + 1) * 16 + n]);
        }
    }
    if (t < 64) lds_b1[t] = b1[t];
    if (t < 16) lds_b2[t] = b2[t];

    const int k = t >> 2, c4 = (t & 3) * 4;  // one item per thread per slice

#define STAGE3(PTR, BASE, KSTR, CH) do {                                       \
        const float4 v = *(const float4*)((PTR) + (BASE) + k * (KSTR) + c4);   \
        *(uint2*)(lds_in + k * 200 + (CH) + c4) =                              \
            make_uint2(pk2(v.x, v.y), pk2(v.z, v.w));                          \
    } while (0)

    for (int it = 0; it < 9; ++it) {
        const int g = blockIdx.x * 9 + it;                 // 0..9215
        const int b = g / 2304, rg = g % 2304, i = rg / 48, j = rg % 48;
        const float* xb2 = x2 + b * 36864;                 // x2[b,m,n,c] = m*768+n*16+c
        const float* xb3 = x3 + b * 1769472;               // x3[b,a,m,n,c] = a*36864+m*768+n*16+c
        __syncthreads();  // previous tile's readers done before restage
        STAGE3(xb2, i * 768 + j * 16, 0,       0);   // q0 x2[b,i,j]
        STAGE3(xb3, i * 36864 + j * 768, 16,   16);  // q0 x3[b,i,j,k]
        STAGE3(xb2, i * 768, 16,               32);  // q1 x2[b,i,k]
        STAGE3(xb3, i * 36864 + j * 16, 768,   48);  // q1 x3[b,i,k,j]
        STAGE3(xb2, j * 768 + i * 16, 0,       64);  // q2 x2[b,j,i]
        STAGE3(xb3, j * 36864 + i * 768, 16,   80);  // q2 x3[b,j,i,k]
        STAGE3(xb2, i * 16, 768,               96);  // q3 x2[b,k,i]
        STAGE3(xb3, i * 768 + j * 16, 36864,   112); // q3 x3[b,k,i,j]
        STAGE3(xb2, j * 768, 16,               128); // q4 x2[b,j,k]
        STAGE3(xb3, j * 36864 + i * 16, 768,   144); // q4 x3[b,j,k,i]
        STAGE3(xb2, j * 16, 768,               160); // q5 x2[b,k,j]
        STAGE3(xb3, j * 768 + i * 16, 36864,   176); // q5 x3[b,k,j,i]
        __syncthreads();
        mlp_head<6>(lds_in, lds_w1t, lds_w2t, lds_b1, lds_b2, lds_h,
                    out + (size_t)g * 768);
    }
#undef STAGE3
}

// ---------------------------------------------------------------------------
// y2: rows (b,i,j).  in128 = [x1[b,i] | x2[b,i,j] | red3(b,i,j) |
//                             x1[b,j] | x2[b,j,i] | red3(b,j,i)]
// red3 = masked max/min over k of x3 (mask: i,j,k pairwise distinct),
// computed in-kernel (no workspace).  One wg per (b,i).
// ---------------------------------------------------------------------------
__global__ __launch_bounds__(192) void y2_kernel(
    const float* __restrict__ x1, const float* __restrict__ x2,
    const float* __restrict__ x3,
    const float* __restrict__ W1, const float* __restrict__ b1,
    const float* __restrict__ W2, const float* __restrict__ b2,
    float* __restrict__ out)
{
    __shared__ __align__(16) unsigned short lds_in[48 * 136];
    __shared__ __align__(16) unsigned short lds_w1t[64 * 136];
    __shared__ __align__(16) unsigned short lds_w2t[16 * 72];
    __shared__ __align__(16) unsigned short lds_h[48 * 72];
    __shared__ float lds_b1[64];
    __shared__ float lds_b2[16];
    const int t = threadIdx.x;
    const int b = blockIdx.x / 48, i = blockIdx.x % 48;

#pragma unroll 2
    for (int p = 0; p < 22; ++p) {
        int e = p * 192 + t;
        if (e < 4096) {
            int h = e & 63, c2 = e >> 6;  // c2 in [0,64)
            *(unsigned int*)(lds_w1t + h * 136 + 2 * c2) =
                pk2(W1[(2 * c2) * 64 + h], W1[(2 * c2 + 1) * 64 + h]);
        }
    }
    for (int p = 0; p < 3; ++p) {
        int e = p * 192 + t;
        if (e < 512) {
            int n = e & 15, k2 = e >> 4;
            *(unsigned int*)(lds_w2t + n * 72 + 2 * k2) =
                pk2(W2[(2 * k2) * 16 + n], W2[(2 * k2 + 1) * 16 + n]);
        }
    }
    if (t < 64) lds_b1[t] = b1[t];
    if (t < 16) lds_b2[t] = b2[t];

    const int j = t >> 2, c4 = (t & 3) * 4;
    const float* xb2 = x2 + b * 36864;

#define STAGE2(PTR, BASE, JSTR, CH) do {                                       \
        const float4 v = *(const float4*)((PTR) + (BASE) + j * (JSTR) + c4);   \
        *(uint2*)(lds_in + j * 136 + (CH) + c4) =                              \
            make_uint2(pk2(v.x, v.y), pk2(v.z, v.w));                          \
    } while (0)

    STAGE2(x1, b * 768 + i * 16, 0,  0);   // x1[b,i]
    STAGE2(xb2, i * 768, 16,         16);  // x2[b,i,j]
    STAGE2(x1, b * 768, 16,          64);  // x1[b,j]
    STAGE2(xb2, i * 16, 768,         80);  // x2[b,j,i]
#undef STAGE2

    {   // masked reductions over k (exact reference semantics: max(x*m), min(x*m+(1-m)))
        const float* pa = x3 + b * 1769472 + (i * 48 + j) * 768 + c4;
        const float* pb = x3 + b * 1769472 + (j * 48 + i) * 768 + c4;
        float exa[4], faa[4], exb[4], fab[4];
#pragma unroll
        for (int u = 0; u < 4; ++u) {
            exa[u] = -__builtin_inff(); faa[u] = __builtin_inff();
            exb[u] = -__builtin_inff(); fab[u] = __builtin_inff();
        }
        for (int kk = 0; kk < 48; ++kk) {
            const bool m = (i != j) & (i != kk) & (j != kk);
            const float4 va = *(const float4*)(pa + kk * 16);
            const float4 vb = *(const float4*)(pb + kk * 16);
            const float av[4] = {va.x, va.y, va.z, va.w};
            const float bv[4] = {vb.x, vb.y, vb.z, vb.w};
#pragma unroll
            for (int u = 0; u < 4; ++u) {
                exa[u] = fmaxf(exa[u], m ? av[u] : 0.f);
                faa[u] = fminf(faa[u], m ? av[u] : 1.f);
                exb[u] = fmaxf(exb[u], m ? bv[u] : 0.f);
                fab[u] = fminf(fab[u], m ? bv[u] : 1.f);
            }
        }
#pragma unroll
        for (int u = 0; u < 4; ++u) {
            const int c = c4 + u;
            *(unsigned int*)(lds_in + j * 136 + 32 + 2 * c) = pk2(exa[u], faa[u]);
            *(unsigned int*)(lds_in + j * 136 + 96 + 2 * c) = pk2(exb[u], fab[u]);
        }
    }
    __syncthreads();
    mlp_head<4>(lds_in, lds_w1t, lds_w2t, lds_b1, lds_b2, lds_h,
                out + (size_t)blockIdx.x * 768);
}

// ---------------------------------------------------------------------------
// y0 + y1 (tiny): blocks 0..3 do y1 for b=blockIdx; blocks 4..7 do y0.
// ---------------------------------------------------------------------------
__global__ __launch_bounds__(128) void y01_kernel(
    const float* __restrict__ x0, const float* __restrict__ x1,
    const float* __restrict__ x2,
    const float* __restrict__ W1_0, const float* __restrict__ b1_0,
    const float* __restrict__ W2_0, const float* __restrict__ b2_0,
    const float* __restrict__ W1_1, const float* __restrict__ b1_1,
    const float* __restrict__ W2_1, const float* __restrict__ b2_1,
    float* __restrict__ out)
{
    __shared__ float w1[64 * 64];
    __shared__ float w2[64 * 16];
    __shared__ float bb1[64];
    __shared__ float bb2[16];
    __shared__ float hbuf[48 * 64];
    const int t = threadIdx.x;
    if (blockIdx.x < 4) {
        const int b = blockIdx.x;
        for (int e = t; e < 4096; e += 128) w1[e] = W1_1[e];
        for (int e = t; e < 1024; e += 128) w2[e] = W2_1[e];
        if (t < 64) bb1[t] = b1_1[t];
        if (t < 16) bb2[t] = b2_1[t];
        __syncthreads();
        if (t < 96) {
            const int i = t % 48, half = t / 48;
            float ex[16], fa[16];
#pragma unroll
            for (int c = 0; c < 16; ++c) { ex[c] = -__builtin_inff(); fa[c] = __builtin_inff(); }
            const float* px = x2 + (b * 48 + i) * 768;
            for (int jj = 0; jj < 48; ++jj) {
                const bool m = (jj != i);
#pragma unroll
                for (int c = 0; c < 16; ++c) {
                    const float v = px[jj * 16 + c];
                    ex[c] = fmaxf(ex[c], m ? v : 0.f);
                    fa[c] = fminf(fa[c], m ? v : 1.f);
                }
            }
            float t1[64];
#pragma unroll
            for (int c = 0; c < 16; ++c) t1[c] = x0[b * 16 + c];
#pragma unroll
            for (int c = 0; c < 16; ++c) t1[16 + c] = x1[(b * 48 + i) * 16 + c];
#pragma unroll
            for (int c = 0; c < 16; ++c) { t1[32 + 2 * c] = ex[c]; t1[33 + 2 * c] = fa[c]; }
            float hh[32];
#pragma unroll
            for (int u = 0; u < 32; ++u) hh[u] = bb1[half * 32 + u];
#pragma unroll
            for (int c = 0; c < 64; ++c) {
                const float tc = t1[c];
#pragma unroll
                for (int u = 0; u < 32; ++u)
                    hh[u] = fmaf(tc, w1[c * 64 + half * 32 + u], hh[u]);
            }
#pragma unroll
            for (int u = 0; u < 32; ++u) hbuf[i * 64 + half * 32 + u] = fmaxf(hh[u], 0.f);
        }
        __syncthreads();
        if (t < 48) {
            const int i = t;
            float acc[16];
#pragma unroll
            for (int o = 0; o < 16; ++o) acc[o] = bb2[o];
            for (int h2 = 0; h2 < 64; ++h2) {
                const float vh = hbuf[i * 64 + h2];
#pragma unroll
                for (int o = 0; o < 16; ++o) acc[o] = fmaf(vh, w2[h2 * 16 + o], acc[o]);
            }
#pragma unroll
            for (int o = 0; o < 16; ++o)
                out[64 + (b * 48 + i) * 16 + o] = sigmoidf_(acc[o]);
        }
    } else {
        const int b = blockIdx.x - 4;
        for (int e = t; e < 3072; e += 128) w1[e] = W1_0[e];
        for (int e = t; e < 1024; e += 128) w2[e] = W2_0[e];
        if (t < 64) bb1[t] = b1_0[t];
        if (t < 16) bb2[t] = b2_0[t];
        __syncthreads();
        if (t < 64) {
            float ex[16], fa[16];
#pragma unroll
            for (int c = 0; c < 16; ++c) { ex[c] = -__builtin_inff(); fa[c] = __builtin_inff(); }
            const float* px = x1 + b * 768;
            for (int n = 0; n < 48; ++n) {
#pragma unroll
                for (int c = 0; c < 16; ++c) {
                    const float v = px[n * 16 + c];
                    ex[c] = fmaxf(ex[c], v);
                    fa[c] = fminf(fa[c], v);
                }
            }
            float t0[48];
#pragma unroll
            for (int c = 0; c < 16; ++c) t0[c] = x0[b * 16 + c];
#pragma unroll
            for (int c = 0; c < 16; ++c) { t0[16 + 2 * c] = ex[c]; t0[17 + 2 * c] = fa[c]; }
            float a = bb1[t];
#pragma unroll
            for (int c = 0; c < 48; ++c) a = fmaf(t0[c], w1[c * 64 + t], a);
            hbuf[t] = fmaxf(a, 0.f);
        }
        __syncthreads();
        if (t < 16) {
            float a = bb2[t];
            for (int h2 = 0; h2 < 64; ++h2) a = fmaf(hbuf[h2], w2[h2 * 16 + t], a);
            out[b * 16 + t] = sigmoidf_(a);
        }
    }
}

// ---------------------------------------------------------------------------
extern "C" void kernel_launch(void* const* d_in, const int* in_sizes, int n_in,
                              void* d_out, int out_size, void* d_ws, size_t ws_size,
                              hipStream_t stream) {
    (void)in_sizes; (void)n_in; (void)d_ws; (void)ws_size; (void)out_size;
    const float* x0 = (const float*)d_in[0];
    const float* x1 = (const float*)d_in[1];
    const float* x2 = (const float*)d_in[2];
    const float* x3 = (const float*)d_in[3];
    const float* W1_0 = (const float*)d_in[4];
    const float* b1_0 = (const float*)d_in[5];
    const float* W2_0 = (const float*)d_in[6];
    const float* b2_0 = (const float*)d_in[7];
    const float* W1_1 = (const float*)d_in[8];
    const float* b1_1 = (const float*)d_in[9];
    const float* W2_1 = (const float*)d_in[10];
    const float* b2_1 = (const float*)d_in[11];
    const float* W1_2 = (const float*)d_in[12];
    const float* b1_2 = (const float*)d_in[13];
    const float* W2_2 = (const float*)d_in[14];
    const float* b2_2 = (const float*)d_in[15];
    const float* W1_3 = (const float*)d_in[16];
    const float* b1_3 = (const float*)d_in[17];
    const float* W2_3 = (const float*)d_in[18];
    const float* b2_3 = (const float*)d_in[19];
    float* out = (float*)d_out;

    // Output layout: y0 [0,64) | y1 [64,3136) | y2 [3136,150592) | y3 [150592, 7228480)
    y3_kernel<<<1024, 192, 0, stream>>>(x2, x3, W1_3, b1_3, W2_3, b2_3, out + 150592);
    y2_kernel<<<192, 192, 0, stream>>>(x1, x2, x3, W1_2, b1_2, W2_2, b2_2, out + 3136);
    y01_kernel<<<8, 128, 0, stream>>>(x0, x1, x2, W1_0, b1_0, W2_0, b2_0,
                                      W1_1, b1_1, W2_1, b2_1, out);
}